// Round 4
// baseline (109.966 us; speedup 1.0000x reference)
//
#include <hip/hip_runtime.h>

// SparseLinear: out[4096,256] = COO @ weight[32000,256] + bias (fp32).
// Round-4: output-column slicing for per-XCD L2 residency.
//   Weight is reshuffled (prep) into slice-major bf16: wb[s][row][32 cols],
//   2 MB per slice -> fits a single XCD's 4 MiB L2. Main grid encodes
//   slice = blockIdx & 7; round-robin block->XCD dispatch pins slice s to
//   XCD s, so gathers hit L2 (34.5 TB/s) instead of fabric/L3 (~6 TB/s).
//   One wave per (row, slice): per load instruction, 16 lanes x 4B read one
//   nnz's 64B slice-row (4 nnz / instruction); shfl_xor reduce across the
//   4 nnz groups; lanes 0-15 write the 128B output slice + bias.

constexpr int BATCH = 4096;

__device__ inline unsigned short f2bf(float f) {   // fp32 -> bf16 RNE
    unsigned u = __float_as_uint(f);
    unsigned r = (u + 0x7FFFu + ((u >> 16) & 1u)) >> 16;
    return (unsigned short)r;
}

// Fused: (a) weight fp32 -> slice-major bf16, (b) CSR row_ptr build.
// Conversion: one wave per weight row; lane l holds cols 4l..4l+3
// (slice = l>>3, in-slice offset = (l&7)*4) -> one ushort4 store.
__global__ __launch_bounds__(256) void prep_kernel(
    const float* __restrict__ weight,          // [in_f, 256] fp32
    unsigned short* __restrict__ wb,           // [8][in_f][32] bf16 out (ws)
    const int* __restrict__ row_idx, int nnz,
    int* __restrict__ ptr,                     // [4097] out (ws)
    int in_f, int conv_blocks)
{
    if ((int)blockIdx.x < conv_blocks) {
        const int wave = threadIdx.x >> 6;
        const int lane = threadIdx.x & 63;
        const int r    = blockIdx.x * 4 + wave;
        if (r < in_f) {
            const float4 f = reinterpret_cast<const float4*>(weight)[r * 64 + lane];
            ushort4 o;
            o.x = f2bf(f.x); o.y = f2bf(f.y); o.z = f2bf(f.z); o.w = f2bf(f.w);
            const int slice = lane >> 3;
            const size_t idx4 = ((size_t)slice * in_f + r) * 8 + (lane & 7);
            reinterpret_cast<ushort4*>(wb)[idx4] = o;
        }
    } else {
        const int i = (blockIdx.x - conv_blocks) * 256 + threadIdx.x;
        if (i >= nnz) return;
        const int r  = row_idx[i];
        const int rn = (i + 1 < nnz) ? row_idx[i + 1] : BATCH;
        for (int rr = r + 1; rr <= rn; ++rr) ptr[rr] = i + 1;
        if (i == 0)
            for (int rr = 0; rr <= r; ++rr) ptr[rr] = 0;
    }
}

__global__ __launch_bounds__(256, 8) void spmm_sliced(
    const int*            __restrict__ col_idx,
    const float*          __restrict__ vals,
    const unsigned short* __restrict__ wb,     // [8][in_f][32] bf16
    const float*          __restrict__ bias,   // [256]
    const int*            __restrict__ ptr,    // [4097]
    float*                __restrict__ out,    // [4096, 256]
    int nnz, int in_f)
{
    const int wave  = threadIdx.x >> 6;
    const int lane  = threadIdx.x & 63;
    const int slice = blockIdx.x & 7;          // -> XCD (round-robin dispatch)
    const int r     = (blockIdx.x >> 3) * 4 + wave;

    const int start = ptr[r];
    const int end   = ptr[r + 1];

    const int j    = lane >> 4;                // nnz sub-index within round, 0..3
    const int cpos = lane & 15;                // uint (= 2 bf16 cols) within slice

    const unsigned* __restrict__ Ws =
        reinterpret_cast<const unsigned*>(wb) + (size_t)slice * in_f * 16;

    float ax = 0.f, ay = 0.f;

    int k = start;
    // 16 nnz per iteration: 4 gather rounds kept in flight.
    for (; k + 16 <= end; k += 16) {
        #pragma unroll
        for (int t = 0; t < 4; ++t) {
            const int   kk = k + t * 4 + j;
            const int   c  = col_idx[kk];
            const float v  = vals[kk];
            const unsigned w = Ws[(size_t)c * 16 + cpos];
            ax = fmaf(v, __uint_as_float(w << 16),          ax);
            ay = fmaf(v, __uint_as_float(w & 0xFFFF0000u), ay);
        }
    }
    // remainder in rounds of 4 with predication
    for (; k < end; k += 4) {
        const int   kk    = k + j;
        const bool  valid = kk < end;
        const int   c     = col_idx[valid ? kk : (nnz - 1)];
        const float v     = valid ? vals[kk] : 0.0f;
        const unsigned w  = Ws[(size_t)c * 16 + cpos];
        ax = fmaf(v, __uint_as_float(w << 16),          ax);
        ay = fmaf(v, __uint_as_float(w & 0xFFFF0000u), ay);
    }

    // reduce the 4 nnz groups (lanes cpos, cpos+16, cpos+32, cpos+48)
    ax += __shfl_xor(ax, 16); ax += __shfl_xor(ax, 32);
    ay += __shfl_xor(ay, 16); ay += __shfl_xor(ay, 32);

    if (lane < 16) {
        const float2 b = reinterpret_cast<const float2*>(bias)[slice * 16 + cpos];
        float2 o; o.x = ax + b.x; o.y = ay + b.y;
        reinterpret_cast<float2*>(out)[(size_t)r * 128 + slice * 16 + cpos] = o;
    }
}

extern "C" void kernel_launch(void* const* d_in, const int* in_sizes, int n_in,
                              void* d_out, int out_size, void* d_ws, size_t ws_size,
                              hipStream_t stream)
{
    const int*   row_idx = (const int*)  d_in[0];
    const int*   col_idx = (const int*)  d_in[1];
    const float* vals    = (const float*)d_in[2];
    const float* weight  = (const float*)d_in[3];
    const float* bias    = (const float*)d_in[4];
    float*       out     = (float*)      d_out;
    const int    nnz     = in_sizes[0];
    const int    in_f    = in_sizes[3] / 256;    // 32000

    unsigned short* wb      = (unsigned short*)d_ws;             // 16.4 MB
    int*            row_ptr = (int*)((char*)d_ws + (32u << 20)); // @32 MiB

    const int conv_blocks = (in_f + 3) / 4;              // 4 rows/block
    const int rptr_blocks = (nnz + 255) / 256;

    hipLaunchKernelGGL(prep_kernel, dim3(conv_blocks + rptr_blocks), dim3(256), 0, stream,
                       weight, wb, row_idx, nnz, row_ptr, in_f, conv_blocks);
    hipLaunchKernelGGL(spmm_sliced, dim3((BATCH / 4) * 8), dim3(256), 0, stream,
                       col_idx, vals, wb, bias, row_ptr, out, nnz, in_f);
}